// Round 4
// baseline (406.558 us; speedup 1.0000x reference)
//
#include <hip/hip_runtime.h>

// ANI symmetry functions: radial scatter-add AEV + angular feature map.
// Round 7 (atomic-SCOPE round):
//  - Mechanism re-read of the 138 us atomic floor: radial-only WRITE_SIZE
//    was 95 MB on an 8.4 MB accumulator = ~30 B L2-egress per atomic.
//    Device-scope atomicAdd WRITES THROUGH L2 and RMWs at the shared
//    coherence point -> flat 23 G/s. Round 2's replicas failed because
//    they changed placement, NOT scope - every RMW still crossed the
//    fabric.
//  - This round: per-XCD replicas + WORKGROUP-SCOPE u64 atomics + replica
//    index from the PHYSICAL XCD id (s_getreg HW_REG_XCC_ID, HW-verified
//    on MI355X). Workgroup-scope atomics execute in the local TCC (L2),
//    cached; each replica line is touched by exactly one XCD, so L2
//    residency is coherent by construction regardless of block->XCD
//    mapping. L2 writeback at kernel end makes convert see the data.
//  - Fallback: if ws can't hold 8 replicas, single-acc device-scope path
//    (correctness never depends on ws_size).
//  - Keep: fusion, group-of-8 role interleave, NT angular stream (now
//    actively protects L2 for hot replica lines).
//  - Disambiguator: fused WRITE_SIZE ~230-270 MB & fused << 167 us =>
//    scope worked; fused ~190-200 us => workgroup scope still routes to
//    the coherence point, revert next round.

#define N_ATOMS 50000
#define N_ELEM 7
#define RADIAL_DIV 8
#define NROWS (N_ATOMS * N_ELEM)

constexpr float RADIAL_CUTOFF = 5.1f;
constexpr float ANGULAR_CUTOFF = 3.5f;
constexpr float ETA_R = 19.7f;
constexpr float ETA_A = 12.5f;
constexpr float ZETA = 14.1f;
constexpr float PI_F = 3.14159265358979323846f;
constexpr float FP_SCALE = 4096.0f;          // 2^12 fixed-point scale
constexpr float FP_INV = 1.0f / 4096.0f;
constexpr float SHELL_STEP = 0.5375f;        // (5.1-0.8)/8
constexpr float INV_SHELL_STEP = 1.0f / 0.5375f;

// ShfZ[j] = (j+0.5)*pi/4 ; precomputed cos/sin:
__device__ __constant__ float CSZ[4] = { 0.9238795325f,  0.3826834324f, -0.3826834324f, -0.9238795325f };
__device__ __constant__ float SNZ[4] = { 0.3826834324f,  0.9238795325f,  0.9238795325f,  0.3826834324f };

#define BLK 256

typedef __attribute__((ext_vector_type(4))) float f4;

// acc layout: [R][NROWS][3] u64. Group g holds shells 2g..2g+3 as 4 x u16
// lanes. Any 3-shell window (eta_R=19.7 => only 3 shells non-negligible)
// fits in ONE group => 1 u64 atomic per row-update, 2 per pair.
template <bool XCD_REP>
__global__ __launch_bounds__(BLK) void fused_kernel(
        const float* __restrict__ r_ij,        // [P]
        const int* __restrict__ pair_idx,      // [2, P]
        const int* __restrict__ Z,             // [N_ATOMS]
        unsigned long long* __restrict__ acc,  // [R, NROWS, 3]
        int P,
        const float* __restrict__ vec12,       // [2, T, 3]
        float* __restrict__ ang,               // [T, 32]
        int T,
        int nRad, int nAng) {
    __shared__ float sm[BLK * 33];             // 33-stride pad kills bank conflicts
    int bid = blockIdx.x;
    int tid = threadIdx.x;

    // Role alternates per GROUP of 8 blocks so each role spans all 8 XCDs
    // (bid%8 == XCD under round-robin dispatch). Even groups: angular,
    // odd groups: radial. Leftover (partial-group) blocks handled after.
    int fullG = (min(nRad, nAng)) >> 3;        // full groups per role
    int base = fullG * 16;                     // paired region in blocks
    bool isAng;
    int id;
    if (bid < base) {
        int grp = bid >> 3;
        isAng = ((grp & 1) == 0);
        id = (grp >> 1) * 8 + (bid & 7);
    } else {
        int l = bid - base;
        int angLeft = nAng - fullG * 8;
        if (l < angLeft) { isAng = true;  id = fullG * 8 + l; }
        else             { isAng = false; id = fullG * 8 + (l - angLeft); }
    }

    if (!isAng) {
        // ---------------- radial tile ----------------
        int t = id * BLK + tid;
        if (t >= P) return;
        float d = __builtin_nontemporal_load(r_ij + t);
        float fc = (d <= RADIAL_CUTOFF)
                       ? (0.5f * __cosf(PI_F * d * (1.0f / RADIAL_CUTOFF)) + 0.5f)
                       : 0.0f;

        // nearest-shell window [a, a+2], a in [0,5]
        float x = (d - 0.8f) * INV_SHELL_STEP;
        int k0 = (int)(x + 0.5f);
        k0 = min(max(k0, 1), 6);
        int a = k0 - 1;
        int g = a >> 1;                        // owning group: shells 2g..2g+3 cover a..a+2
        int sh = (a & 1) << 4;                 // bit offset of lane (a-2g)

        unsigned long long w = 0ull;
        #pragma unroll
        for (int j = 0; j < 3; j++) {
            float diff = d - (0.8f + SHELL_STEP * (float)(a + j));
            float gv = 0.25f * __expf(-ETA_R * diff * diff) * fc;   // [0, 0.25]
            unsigned int q = (unsigned int)(gv * FP_SCALE + 0.5f);
            w |= (unsigned long long)q << (16 * j);
        }
        w <<= sh;
        if (w == 0ull) return;                 // d near cutoff: all three quantize to 0

        int i0 = __builtin_nontemporal_load(pair_idx + t);
        int i1 = __builtin_nontemporal_load(pair_idx + P + t);
        int s0 = Z[i0];
        int s1 = Z[i1];
        size_t o0 = ((size_t)i0 * N_ELEM + s1) * 3 + g;   // index12[0] uses partner species
        size_t o1 = ((size_t)i1 * N_ELEM + s0) * 3 + g;

        if constexpr (XCD_REP) {
            // Physical XCD id -> replica. All waves of this block share one
            // CU => one XCD => replica lines are XCD-private by construction;
            // workgroup-scope atomics execute cached in the local TCC (L2).
            unsigned int xcc;
            asm("s_getreg_b32 %0, hwreg(HW_REG_XCC_ID)" : "=s"(xcc));
            unsigned long long* accr = acc + (size_t)(xcc & 7u) * ((size_t)NROWS * 3);
            __hip_atomic_fetch_add(accr + o0, w, __ATOMIC_RELAXED, __HIP_MEMORY_SCOPE_WORKGROUP);
            __hip_atomic_fetch_add(accr + o1, w, __ATOMIC_RELAXED, __HIP_MEMORY_SCOPE_WORKGROUP);
        } else {
            atomicAdd(acc + o0, w);
            atomicAdd(acc + o1, w);
        }
        return;
    }

    // ---------------- angular tile ----------------
    int t = id * BLK + tid;
    float vals[32];
    if (t < T) {
        const float* v1 = vec12 + 3ull * (size_t)t;
        const float* v2 = vec12 + 3ull * (size_t)T + 3ull * (size_t)t;
        float x1 = __builtin_nontemporal_load(v1 + 0);
        float y1 = __builtin_nontemporal_load(v1 + 1);
        float z1 = __builtin_nontemporal_load(v1 + 2);
        float x2 = __builtin_nontemporal_load(v2 + 0);
        float y2 = __builtin_nontemporal_load(v2 + 1);
        float z2 = __builtin_nontemporal_load(v2 + 2);

        float d1 = sqrtf(x1 * x1 + y1 * y1 + z1 * z1);
        float d2 = sqrtf(x2 * x2 + y2 * y2 + z2 * z2);
        float dot = x1 * x2 + y1 * y2 + z1 * z2;
        float cost = 0.95f * dot / (d1 * d2);                  // |cost| <= 0.95
        float sint = sqrtf(fmaxf(0.0f, 1.0f - cost * cost));   // theta in [0,pi] -> sin >= 0

        float fc1 = (d1 <= ANGULAR_CUTOFF) ? (0.5f * __cosf(PI_F * d1 * (1.0f / ANGULAR_CUTOFF)) + 0.5f) : 0.0f;
        float fc2 = (d2 <= ANGULAR_CUTOFF) ? (0.5f * __cosf(PI_F * d2 * (1.0f / ANGULAR_CUTOFF)) + 0.5f) : 0.0f;
        float fc = fc1 * fc2;

        float davg = 0.5f * (d1 + d2);
        float frad[8];
        #pragma unroll
        for (int k = 0; k < 8; k++) {
            float diff = davg - (0.8f + 0.3375f * (float)k);
            frad[k] = __expf(-ETA_A * diff * diff);
        }
        #pragma unroll
        for (int j = 0; j < 4; j++) {
            // cos(theta - ShfZ[j]) = cost*cos(s) + sint*sin(s)
            float c = 0.5f * (1.0f + cost * CSZ[j] + sint * SNZ[j]);   // in [0.025, 1]
            float base2 = 2.0f * __powf(c, ZETA) * fc;
            #pragma unroll
            for (int k = 0; k < 8; k++) vals[j * 8 + k] = base2 * frad[k];
        }
    } else {
        #pragma unroll
        for (int k = 0; k < 32; k++) vals[k] = 0.0f;
    }

    #pragma unroll
    for (int k = 0; k < 32; k++) sm[tid * 33 + k] = vals[k];
    __syncthreads();

    // Coalesced NON-TEMPORAL write of the block's [BLK,32] region:
    // 8 float4 per thread, touch-once stream kept out of L2.
    size_t obase = (size_t)id * BLK * 32;
    size_t lim = (size_t)T * 32;
    #pragma unroll
    for (int it = 0; it < 8; it++) {
        int f = it * BLK + tid;                  // float4 index within block
        int row = f >> 3;                        // f*4/32
        int col = (f & 7) * 4;
        f4 o;
        o.x = sm[row * 33 + col + 0];
        o.y = sm[row * 33 + col + 1];
        o.z = sm[row * 33 + col + 2];
        o.w = sm[row * 33 + col + 3];
        size_t gidx = obase + (size_t)f * 4;
        if (gidx < lim)
            __builtin_nontemporal_store(o, reinterpret_cast<f4*>(ang) + (gidx >> 2));
    }
}

// Reconstruct f32 row: sum R replicas of 3 overlapping u64 groups.
__global__ void convert_kernel(const unsigned long long* __restrict__ acc,
                               float* __restrict__ aev, int nrows, int R) {
    int r = blockIdx.x * blockDim.x + threadIdx.x;
    if (r >= nrows) return;
    unsigned int l0[4] = {0, 0, 0, 0};
    unsigned int l1[4] = {0, 0, 0, 0};
    unsigned int l2[4] = {0, 0, 0, 0};
    for (int rep = 0; rep < R; rep++) {
        const unsigned long long* a = acc + (size_t)rep * nrows * 3 + 3 * (size_t)r;
        unsigned long long g0 = a[0];
        unsigned long long g1 = a[1];
        unsigned long long g2 = a[2];
        #pragma unroll
        for (int j = 0; j < 4; j++) {
            l0[j] += (unsigned int)(g0 >> (16 * j)) & 0xFFFFu;
            l1[j] += (unsigned int)(g1 >> (16 * j)) & 0xFFFFu;
            l2[j] += (unsigned int)(g2 >> (16 * j)) & 0xFFFFu;
        }
    }
    f4 oa, ob;
    oa.x = (float)(l0[0])         * FP_INV;           // shell 0
    oa.y = (float)(l0[1])         * FP_INV;           // shell 1
    oa.z = (float)(l0[2] + l1[0]) * FP_INV;           // shell 2
    oa.w = (float)(l0[3] + l1[1]) * FP_INV;           // shell 3
    ob.x = (float)(l1[2] + l2[0]) * FP_INV;           // shell 4
    ob.y = (float)(l1[3] + l2[1]) * FP_INV;           // shell 5
    ob.z = (float)(l2[2])         * FP_INV;           // shell 6
    ob.w = (float)(l2[3])         * FP_INV;           // shell 7
    f4* o = reinterpret_cast<f4*>(aev + 8ull * (size_t)r);
    __builtin_nontemporal_store(oa, o + 0);
    __builtin_nontemporal_store(ob, o + 1);
}

extern "C" void kernel_launch(void* const* d_in, const int* in_sizes, int n_in,
                              void* d_out, int out_size, void* d_ws, size_t ws_size,
                              hipStream_t stream) {
    const float* r_ij     = (const float*)d_in[0];
    const int*   pair_idx = (const int*)d_in[1];
    const int*   Z        = (const int*)d_in[2];
    const float* vec12    = (const float*)d_in[3];

    const int P = in_sizes[0];           // 1,600,000 pairs
    const int T = in_sizes[3] / 6;       // 1,600,000 triplets

    float* aev = (float*)d_out;                                  // [NROWS, 8]
    float* ang = aev + (size_t)NROWS * RADIAL_DIV;               // [T, 32]

    const size_t repBytes = (size_t)NROWS * 3 * sizeof(unsigned long long); // 8.4 MB
    const bool xcdRep = (ws_size >= 8 * repBytes);
    const int R = xcdRep ? 8 : 1;

    unsigned long long* acc = (unsigned long long*)d_ws;         // [R, NROWS, 3] u64
    hipMemsetAsync(acc, 0, (size_t)R * repBytes, stream);

    const int nRad = (P + BLK - 1) / BLK;
    const int nAng = (T + BLK - 1) / BLK;
    if (xcdRep) {
        fused_kernel<true><<<dim3(nRad + nAng), dim3(BLK), 0, stream>>>(
            r_ij, pair_idx, Z, acc, P, vec12, ang, T, nRad, nAng);
    } else {
        fused_kernel<false><<<dim3(nRad + nAng), dim3(BLK), 0, stream>>>(
            r_ij, pair_idx, Z, acc, P, vec12, ang, T, nRad, nAng);
    }
    convert_kernel<<<dim3((NROWS + 255) / 256), dim3(256), 0, stream>>>(acc, aev, NROWS, R);
}

// Round 5
// 367.621 us; speedup vs baseline: 1.1059x; 1.1059x over previous
//
#include <hip/hip_runtime.h>

// ANI symmetry functions: radial scatter-add AEV + angular feature map.
// Round 8 (merged-role fusion):
//  - Rounds 2/3/4 post-mortem: replicas (device-scope), NT hints, and
//    workgroup-scope+XCC_ID replicas were ALL null against the 138 us
//    atomic floor. WRITE_SIZE stayed ~295 MB (=~30 B write-through per
//    atomic) in every variant => gfx950 global atomics execute
//    memory-side at a fixed ~23 G transactions/s regardless of scope,
//    placement, or cache hints. Transaction count (3.2M = 1 packed u64
//    per row-update, 2 row-updates/pair) is already the scatter minimum.
//    Reverted to single 8.4 MB accumulator + plain atomicAdd.
//  - Remaining lever: the fusion interference term (best fused 165 us vs
//    ideal max(138 atomic, ~55 angular) = 138). Theory: role-split radial
//    blocks have nothing to execute while atomic queues backpressure.
//    Fix: MERGE roles - every block issues its radial tile's 2
//    fire-and-forget atomics (no result use => no waitcnt, wave proceeds
//    immediately), then runs a full angular tile while the transactions
//    drain. Intra-wave hiding instead of cross-block co-residency.
//    Grid halves to 6250 blocks; role branch gone.
//  - Disambiguator: fused ~140-155 => hiding works; fused ~165 => memory
//    -pipe backpressure stalls the wave regardless => structural floor,
//    declare roofline.

#define N_ATOMS 50000
#define N_ELEM 7
#define RADIAL_DIV 8
#define NROWS (N_ATOMS * N_ELEM)

constexpr float RADIAL_CUTOFF = 5.1f;
constexpr float ANGULAR_CUTOFF = 3.5f;
constexpr float ETA_R = 19.7f;
constexpr float ETA_A = 12.5f;
constexpr float ZETA = 14.1f;
constexpr float PI_F = 3.14159265358979323846f;
constexpr float FP_SCALE = 4096.0f;          // 2^12 fixed-point scale
constexpr float FP_INV = 1.0f / 4096.0f;
constexpr float SHELL_STEP = 0.5375f;        // (5.1-0.8)/8
constexpr float INV_SHELL_STEP = 1.0f / 0.5375f;

// ShfZ[j] = (j+0.5)*pi/4 ; precomputed cos/sin:
__device__ __constant__ float CSZ[4] = { 0.9238795325f,  0.3826834324f, -0.3826834324f, -0.9238795325f };
__device__ __constant__ float SNZ[4] = { 0.3826834324f,  0.9238795325f,  0.9238795325f,  0.3826834324f };

#define BLK 256

typedef __attribute__((ext_vector_type(4))) float f4;

// acc layout: [NROWS][3] u64. Group g holds shells 2g..2g+3 as 4 x u16
// lanes. Any 3-shell window (eta_R=19.7 => only 3 shells non-negligible)
// fits in ONE group => 1 u64 atomic per row-update, 2 per pair.
__global__ __launch_bounds__(BLK) void fused_kernel(
        const float* __restrict__ r_ij,        // [P]
        const int* __restrict__ pair_idx,      // [2, P]
        const int* __restrict__ Z,             // [N_ATOMS]
        unsigned long long* __restrict__ acc,  // [NROWS, 3]
        int P,
        const float* __restrict__ vec12,       // [2, T, 3]
        float* __restrict__ ang,               // [T, 32]
        int T) {
    __shared__ float sm[BLK * 33];             // 33-stride pad kills bank conflicts
    int tid = threadIdx.x;
    int t = blockIdx.x * BLK + tid;

    // ---------------- radial phase: issue-and-forget ----------------
    if (t < P) {
        float d = __builtin_nontemporal_load(r_ij + t);
        float fc = (d <= RADIAL_CUTOFF)
                       ? (0.5f * __cosf(PI_F * d * (1.0f / RADIAL_CUTOFF)) + 0.5f)
                       : 0.0f;

        // nearest-shell window [a, a+2], a in [0,5]
        float x = (d - 0.8f) * INV_SHELL_STEP;
        int k0 = (int)(x + 0.5f);
        k0 = min(max(k0, 1), 6);
        int a = k0 - 1;
        int g = a >> 1;                        // owning group: shells 2g..2g+3 cover a..a+2
        int sh = (a & 1) << 4;                 // bit offset of lane (a-2g)

        unsigned long long w = 0ull;
        #pragma unroll
        for (int j = 0; j < 3; j++) {
            float diff = d - (0.8f + SHELL_STEP * (float)(a + j));
            float gv = 0.25f * __expf(-ETA_R * diff * diff) * fc;   // [0, 0.25]
            unsigned int q = (unsigned int)(gv * FP_SCALE + 0.5f);
            w |= (unsigned long long)q << (16 * j);
        }
        w <<= sh;
        if (w != 0ull) {                       // d near cutoff: all three quantize to 0
            int i0 = __builtin_nontemporal_load(pair_idx + t);
            int i1 = __builtin_nontemporal_load(pair_idx + P + t);
            int s0 = Z[i0];
            int s1 = Z[i1];
            // Fire-and-forget: results unused => no s_waitcnt; the wave
            // proceeds into angular compute while these drain.
            atomicAdd(acc + ((size_t)i0 * N_ELEM + s1) * 3 + g, w);   // index12[0] uses partner species
            atomicAdd(acc + ((size_t)i1 * N_ELEM + s0) * 3 + g, w);
        }
    }

    // ---------------- angular phase ----------------
    float vals[32];
    if (t < T) {
        const float* v1 = vec12 + 3ull * (size_t)t;
        const float* v2 = vec12 + 3ull * (size_t)T + 3ull * (size_t)t;
        float x1 = __builtin_nontemporal_load(v1 + 0);
        float y1 = __builtin_nontemporal_load(v1 + 1);
        float z1 = __builtin_nontemporal_load(v1 + 2);
        float x2 = __builtin_nontemporal_load(v2 + 0);
        float y2 = __builtin_nontemporal_load(v2 + 1);
        float z2 = __builtin_nontemporal_load(v2 + 2);

        float d1 = sqrtf(x1 * x1 + y1 * y1 + z1 * z1);
        float d2 = sqrtf(x2 * x2 + y2 * y2 + z2 * z2);
        float dot = x1 * x2 + y1 * y2 + z1 * z2;
        float cost = 0.95f * dot / (d1 * d2);                  // |cost| <= 0.95
        float sint = sqrtf(fmaxf(0.0f, 1.0f - cost * cost));   // theta in [0,pi] -> sin >= 0

        float fc1 = (d1 <= ANGULAR_CUTOFF) ? (0.5f * __cosf(PI_F * d1 * (1.0f / ANGULAR_CUTOFF)) + 0.5f) : 0.0f;
        float fc2 = (d2 <= ANGULAR_CUTOFF) ? (0.5f * __cosf(PI_F * d2 * (1.0f / ANGULAR_CUTOFF)) + 0.5f) : 0.0f;
        float fc = fc1 * fc2;

        float davg = 0.5f * (d1 + d2);
        float frad[8];
        #pragma unroll
        for (int k = 0; k < 8; k++) {
            float diff = davg - (0.8f + 0.3375f * (float)k);
            frad[k] = __expf(-ETA_A * diff * diff);
        }
        #pragma unroll
        for (int j = 0; j < 4; j++) {
            // cos(theta - ShfZ[j]) = cost*cos(s) + sint*sin(s)
            float c = 0.5f * (1.0f + cost * CSZ[j] + sint * SNZ[j]);   // in [0.025, 1]
            float base2 = 2.0f * __powf(c, ZETA) * fc;
            #pragma unroll
            for (int k = 0; k < 8; k++) vals[j * 8 + k] = base2 * frad[k];
        }
    } else {
        #pragma unroll
        for (int k = 0; k < 32; k++) vals[k] = 0.0f;
    }

    #pragma unroll
    for (int k = 0; k < 32; k++) sm[tid * 33 + k] = vals[k];
    __syncthreads();

    // Coalesced NON-TEMPORAL write of the block's [BLK,32] region:
    // 8 float4 per thread, touch-once stream kept out of L2.
    size_t obase = (size_t)blockIdx.x * BLK * 32;
    size_t lim = (size_t)T * 32;
    #pragma unroll
    for (int it = 0; it < 8; it++) {
        int f = it * BLK + tid;                  // float4 index within block
        int row = f >> 3;                        // f*4/32
        int col = (f & 7) * 4;
        f4 o;
        o.x = sm[row * 33 + col + 0];
        o.y = sm[row * 33 + col + 1];
        o.z = sm[row * 33 + col + 2];
        o.w = sm[row * 33 + col + 3];
        size_t gidx = obase + (size_t)f * 4;
        if (gidx < lim)
            __builtin_nontemporal_store(o, reinterpret_cast<f4*>(ang) + (gidx >> 2));
    }
}

// Reconstruct f32 row from 3 overlapping u64 groups.
__global__ void convert_kernel(const unsigned long long* __restrict__ acc,
                               float* __restrict__ aev, int nrows) {
    int r = blockIdx.x * blockDim.x + threadIdx.x;
    if (r >= nrows) return;
    unsigned long long g0 = acc[3 * (size_t)r + 0];
    unsigned long long g1 = acc[3 * (size_t)r + 1];
    unsigned long long g2 = acc[3 * (size_t)r + 2];
    unsigned int l0[4], l1[4], l2[4];
    #pragma unroll
    for (int j = 0; j < 4; j++) {
        l0[j] = (unsigned int)(g0 >> (16 * j)) & 0xFFFFu;
        l1[j] = (unsigned int)(g1 >> (16 * j)) & 0xFFFFu;
        l2[j] = (unsigned int)(g2 >> (16 * j)) & 0xFFFFu;
    }
    f4 oa, ob;
    oa.x = (float)(l0[0])         * FP_INV;           // shell 0
    oa.y = (float)(l0[1])         * FP_INV;           // shell 1
    oa.z = (float)(l0[2] + l1[0]) * FP_INV;           // shell 2
    oa.w = (float)(l0[3] + l1[1]) * FP_INV;           // shell 3
    ob.x = (float)(l1[2] + l2[0]) * FP_INV;           // shell 4
    ob.y = (float)(l1[3] + l2[1]) * FP_INV;           // shell 5
    ob.z = (float)(l2[2])         * FP_INV;           // shell 6
    ob.w = (float)(l2[3])         * FP_INV;           // shell 7
    f4* o = reinterpret_cast<f4*>(aev + 8ull * (size_t)r);
    __builtin_nontemporal_store(oa, o + 0);
    __builtin_nontemporal_store(ob, o + 1);
}

extern "C" void kernel_launch(void* const* d_in, const int* in_sizes, int n_in,
                              void* d_out, int out_size, void* d_ws, size_t ws_size,
                              hipStream_t stream) {
    const float* r_ij     = (const float*)d_in[0];
    const int*   pair_idx = (const int*)d_in[1];
    const int*   Z        = (const int*)d_in[2];
    const float* vec12    = (const float*)d_in[3];

    const int P = in_sizes[0];           // 1,600,000 pairs
    const int T = in_sizes[3] / 6;       // 1,600,000 triplets

    float* aev = (float*)d_out;                                  // [NROWS, 8]
    float* ang = aev + (size_t)NROWS * RADIAL_DIV;               // [T, 32]

    unsigned long long* acc = (unsigned long long*)d_ws;         // [NROWS, 3] u64 = 8.4 MB
    hipMemsetAsync(acc, 0, (size_t)NROWS * 3 * sizeof(unsigned long long), stream);

    const int nRad = (P + BLK - 1) / BLK;
    const int nAng = (T + BLK - 1) / BLK;
    const int nBlk = max(nRad, nAng);
    fused_kernel<<<dim3(nBlk), dim3(BLK), 0, stream>>>(
        r_ij, pair_idx, Z, acc, P, vec12, ang, T);
    convert_kernel<<<dim3((NROWS + 255) / 256), dim3(256), 0, stream>>>(acc, aev, NROWS);
}